// Round 1
// baseline (160.971 us; speedup 1.0000x reference)
//
#include <hip/hip_runtime.h>

// SPD loss: 18-bin histogram over (pred, attr) pairs + tiny double-precision epilogue.
// Memory-bound: 134 MB read -> ~21 us roofline at 6.3 TB/s.

#define N_CLASSES 9
#define N_GROUPS 2
#define NBINS (N_CLASSES * N_GROUPS)   // 18
#define REPLICAS 64                    // one histogram replica per lane of a wave
#define RSTRIDE 33                     // odd stride: bank = (replica + bin) % 32 -> distinct per lane

__global__ __launch_bounds__(256) void spd_hist_kernel(
    const int* __restrict__ preds,
    const int* __restrict__ attrs,
    unsigned int* __restrict__ g_counts,
    int n4, int n)
{
    __shared__ unsigned int lhist[REPLICAS * RSTRIDE];

    // zero LDS histogram
    for (int i = threadIdx.x; i < REPLICAS * RSTRIDE; i += blockDim.x)
        lhist[i] = 0u;
    __syncthreads();

    const int rep = (threadIdx.x & 63) * RSTRIDE;  // per-lane replica: no intra-wave same-address contention
    const int4* __restrict__ p4 = (const int4*)preds;
    const int4* __restrict__ a4 = (const int4*)attrs;

    const int stride = gridDim.x * blockDim.x;
    for (int i = blockIdx.x * blockDim.x + threadIdx.x; i < n4; i += stride) {
        int4 p = p4[i];
        int4 a = a4[i];
        atomicAdd(&lhist[rep + p.x * N_GROUPS + a.x], 1u);
        atomicAdd(&lhist[rep + p.y * N_GROUPS + a.y], 1u);
        atomicAdd(&lhist[rep + p.z * N_GROUPS + a.z], 1u);
        atomicAdd(&lhist[rep + p.w * N_GROUPS + a.w], 1u);
    }

    // scalar tail (n not divisible by 4) — block 0 only
    if (blockIdx.x == 0) {
        for (int i = n4 * 4 + (int)threadIdx.x; i < n; i += (int)blockDim.x) {
            atomicAdd(&lhist[rep + preds[i] * N_GROUPS + attrs[i]], 1u);
        }
    }
    __syncthreads();

    // reduce replicas: thread b (b < 18) sums bin b across all replicas
    if (threadIdx.x < NBINS) {
        unsigned int s = 0u;
        #pragma unroll
        for (int r = 0; r < REPLICAS; ++r)
            s += lhist[r * RSTRIDE + threadIdx.x];
        atomicAdd(&g_counts[threadIdx.x], s);  // device-scope by default
    }
}

__global__ void spd_finalize_kernel(const unsigned int* __restrict__ g_counts,
                                    float* __restrict__ out, double n_total)
{
    if (threadIdx.x == 0 && blockIdx.x == 0) {
        double n1 = 0.0;
        #pragma unroll
        for (int c = 0; c < N_CLASSES; ++c)
            n1 += (double)g_counts[c * N_GROUPS + 1];
        double n0 = n_total - n1;
        double acc = 0.0;
        #pragma unroll
        for (int c = 0; c < N_CLASSES; ++c) {
            double d = (double)g_counts[c * N_GROUPS] / n0
                     - (double)g_counts[c * N_GROUPS + 1] / n1;
            acc += d * d;
        }
        out[0] = (float)acc;
    }
}

extern "C" void kernel_launch(void* const* d_in, const int* in_sizes, int n_in,
                              void* d_out, int out_size, void* d_ws, size_t ws_size,
                              hipStream_t stream)
{
    const int* preds = (const int*)d_in[0];
    const int* attrs = (const int*)d_in[1];
    const int n = in_sizes[0];

    unsigned int* counts = (unsigned int*)d_ws;
    hipMemsetAsync(counts, 0, NBINS * sizeof(unsigned int), stream);

    const int n4 = n / 4;
    const int block = 256;
    // 2048 blocks = 8 waves/block-equivalent oversubscription across 256 CUs; grid-stride handles the rest
    int grid = (n4 + block - 1) / block;
    if (grid > 2048) grid = 2048;
    if (grid < 1) grid = 1;

    spd_hist_kernel<<<grid, block, 0, stream>>>(preds, attrs, counts, n4, n);
    spd_finalize_kernel<<<1, 64, 0, stream>>>(counts, (float*)d_out, (double)n);
}

// Round 2
// 158.841 us; speedup vs baseline: 1.0134x; 1.0134x over previous
//
#include <hip/hip_runtime.h>

// SPD loss: 18-bin (9 class x 2 group) histogram over 16.7M int32 pairs + tiny epilogue.
// R0 lesson: scattered LDS atomics sustain only ~0.5 lane-ops/cy/CU -> 55 us.
// R1: register-packed histogram (2x u64, 9 fields x 7 bits, split by attr),
//     one wave-butterfly flush per thread. Floor = 134 MB read ~= 22 us @ 6.3 TB/s.

#define N_CLASSES 9
#define N_GROUPS 2
#define NBINS (N_CLASSES * N_GROUPS)  // 18
#define GRID_BLOCKS 2048              // 256 thr each -> 524288 threads, 32 items/thread (<=127 field cap)

__global__ __launch_bounds__(256) void spd_hist_kernel(
    const int* __restrict__ preds,
    const int* __restrict__ attrs,
    unsigned int* __restrict__ g_counts,
    int n4, int n)
{
    // per-block packed histogram: lo16 = attr0 count, hi16 = attr1 count
    __shared__ unsigned int lhist[N_CLASSES];
    if (threadIdx.x < N_CLASSES) lhist[threadIdx.x] = 0u;
    __syncthreads();

    // register histogram: 9 fields x 7 bits each; field = pred, acc selected by attr.
    // capacity per field = 127; items/thread = 32 (+tiny tail) -> safe.
    unsigned long long acc0 = 0ull, acc1 = 0ull;

    const int4* __restrict__ p4 = (const int4*)preds;
    const int4* __restrict__ a4 = (const int4*)attrs;
    const int stride = gridDim.x * blockDim.x;

    for (int i = blockIdx.x * blockDim.x + threadIdx.x; i < n4; i += stride) {
        int4 p = p4[i];
        int4 a = a4[i];
        {
            unsigned long long inc = 1ull << (7 * p.x);
            acc0 += (a.x == 0) ? inc : 0ull;
            acc1 += (a.x == 0) ? 0ull : inc;
        }
        {
            unsigned long long inc = 1ull << (7 * p.y);
            acc0 += (a.y == 0) ? inc : 0ull;
            acc1 += (a.y == 0) ? 0ull : inc;
        }
        {
            unsigned long long inc = 1ull << (7 * p.z);
            acc0 += (a.z == 0) ? inc : 0ull;
            acc1 += (a.z == 0) ? 0ull : inc;
        }
        {
            unsigned long long inc = 1ull << (7 * p.w);
            acc0 += (a.w == 0) ? inc : 0ull;
            acc1 += (a.w == 0) ? 0ull : inc;
        }
    }

    // scalar tail (n % 4 != 0), block 0 only — adds <=1 per field, still < 127
    if (blockIdx.x == 0) {
        for (int i = n4 * 4 + (int)threadIdx.x; i < n; i += (int)blockDim.x) {
            unsigned long long inc = 1ull << (7 * preds[i]);
            if (attrs[i] == 0) acc0 += inc; else acc1 += inc;
        }
    }

    // extract fields, pack attr0/attr1 into 16-bit halves of 9 u32s
    unsigned int cnt[N_CLASSES];
    #pragma unroll
    for (int p = 0; p < N_CLASSES; ++p) {
        unsigned int c0 = (unsigned int)(acc0 >> (7 * p)) & 127u;
        unsigned int c1 = (unsigned int)(acc1 >> (7 * p)) & 127u;
        cnt[p] = c0 | (c1 << 16);
    }

    // wave-64 butterfly reduction; 16-bit field max = 64 lanes * ~33 items = ~2k, no carry
    #pragma unroll
    for (int m = 1; m < 64; m <<= 1) {
        #pragma unroll
        for (int p = 0; p < N_CLASSES; ++p)
            cnt[p] += __shfl_xor(cnt[p], m, 64);
    }

    // one flush per wave into per-block LDS (9 lane-atomics per wave — negligible)
    if ((threadIdx.x & 63) == 0) {
        #pragma unroll
        for (int p = 0; p < N_CLASSES; ++p)
            atomicAdd(&lhist[p], cnt[p]);
    }
    __syncthreads();

    // per-block 16-bit field max = 256 thr * ~33 items = ~8.5k < 65536: no overflow.
    // 18 global atomics per block (2048 per bin address total — amortized).
    if (threadIdx.x < NBINS) {
        unsigned int pk = lhist[threadIdx.x >> 1];
        unsigned int v = (threadIdx.x & 1) ? (pk >> 16) : (pk & 0xFFFFu);
        atomicAdd(&g_counts[threadIdx.x], v);
    }
}

__global__ void spd_finalize_kernel(const unsigned int* __restrict__ g_counts,
                                    float* __restrict__ out, double n_total)
{
    if (threadIdx.x == 0 && blockIdx.x == 0) {
        double n1 = 0.0;
        #pragma unroll
        for (int c = 0; c < N_CLASSES; ++c)
            n1 += (double)g_counts[c * N_GROUPS + 1];
        double n0 = n_total - n1;
        double acc = 0.0;
        #pragma unroll
        for (int c = 0; c < N_CLASSES; ++c) {
            double d = (double)g_counts[c * N_GROUPS] / n0
                     - (double)g_counts[c * N_GROUPS + 1] / n1;
            acc += d * d;
        }
        out[0] = (float)acc;
    }
}

extern "C" void kernel_launch(void* const* d_in, const int* in_sizes, int n_in,
                              void* d_out, int out_size, void* d_ws, size_t ws_size,
                              hipStream_t stream)
{
    const int* preds = (const int*)d_in[0];
    const int* attrs = (const int*)d_in[1];
    const int n = in_sizes[0];

    unsigned int* counts = (unsigned int*)d_ws;
    hipMemsetAsync(counts, 0, NBINS * sizeof(unsigned int), stream);

    const int n4 = n / 4;
    const int block = 256;
    int grid = (n4 + block - 1) / block;
    if (grid > GRID_BLOCKS) grid = GRID_BLOCKS;
    if (grid < 1) grid = 1;

    spd_hist_kernel<<<grid, block, 0, stream>>>(preds, attrs, counts, n4, n);
    spd_finalize_kernel<<<1, 64, 0, stream>>>(counts, (float*)d_out, (double)n);
}

// Round 3
// 156.247 us; speedup vs baseline: 1.0302x; 1.0166x over previous
//
#include <hip/hip_runtime.h>

// SPD loss: 18-bin (9 class x 2 group) histogram over 16.7M int32 pairs + tiny epilogue.
// R0 lesson: scattered LDS atomics -> 55 us (wrong theory for the ceiling, right locally).
// R1 lesson: removing LDS atomics changed nothing; L3-warm dispatches also run 55 us.
//   => bottleneck is the global-atomic tail: 2048 blocks x 18 atomicAdds into 18
//      consecutive words = 1-2 cache lines = one serialized L2 channel (~147k cy).
// R2: NO global atomics. Each block stores 18 exact partials to its own d_ws slot;
//     a tiny second kernel reduces 2048x18 partials + computes the double epilogue.

#define N_CLASSES 9
#define N_GROUPS 2
#define NBINS (N_CLASSES * N_GROUPS)  // 18
#define GRID_BLOCKS 2048
#define CHUNK 31                      // int4-iterations per register-flush window: 124 items < 127 (7-bit cap)

__global__ __launch_bounds__(256) void spd_hist_kernel(
    const int* __restrict__ preds,
    const int* __restrict__ attrs,
    unsigned int* __restrict__ partials,  // [gridDim.x][NBINS]
    int n4, int n)
{
    __shared__ unsigned int lh0[N_CLASSES];  // block counts, group 0
    __shared__ unsigned int lh1[N_CLASSES];  // block counts, group 1
    if (threadIdx.x < N_CLASSES) { lh0[threadIdx.x] = 0u; lh1[threadIdx.x] = 0u; }
    __syncthreads();

    // per-thread 16-bit packed counters: lo16 = group0, hi16 = group1
    unsigned int cnt[N_CLASSES];
    #pragma unroll
    for (int p = 0; p < N_CLASSES; ++p) cnt[p] = 0u;

    const int4* __restrict__ p4 = (const int4*)preds;
    const int4* __restrict__ a4 = (const int4*)attrs;
    const int stride = gridDim.x * blockDim.x;

    int i = blockIdx.x * blockDim.x + threadIdx.x;
    while (i < n4) {
        // 7-bit-field register histogram over a bounded window (<=124 items/field)
        unsigned long long acc0 = 0ull, acc1 = 0ull;
        int lim = CHUNK;
        for (; i < n4 && lim; i += stride, --lim) {
            int4 p = p4[i];
            int4 a = a4[i];
            {
                unsigned long long inc = 1ull << (7 * p.x);
                acc0 += (a.x == 0) ? inc : 0ull;
                acc1 += (a.x == 0) ? 0ull : inc;
            }
            {
                unsigned long long inc = 1ull << (7 * p.y);
                acc0 += (a.y == 0) ? inc : 0ull;
                acc1 += (a.y == 0) ? 0ull : inc;
            }
            {
                unsigned long long inc = 1ull << (7 * p.z);
                acc0 += (a.z == 0) ? inc : 0ull;
                acc1 += (a.z == 0) ? 0ull : inc;
            }
            {
                unsigned long long inc = 1ull << (7 * p.w);
                acc0 += (a.w == 0) ? inc : 0ull;
                acc1 += (a.w == 0) ? 0ull : inc;
            }
        }
        #pragma unroll
        for (int p = 0; p < N_CLASSES; ++p) {
            unsigned int c0 = (unsigned int)(acc0 >> (7 * p)) & 127u;
            unsigned int c1 = (unsigned int)(acc1 >> (7 * p)) & 127u;
            cnt[p] += c0 | (c1 << 16);
        }
    }

    // scalar tail (n % 4 != 0), block 0 only: <=3 items total
    if (blockIdx.x == 0) {
        for (int t = n4 * 4 + (int)threadIdx.x; t < n; t += (int)blockDim.x)
            cnt[preds[t]] += (attrs[t] == 0) ? 1u : 0x10000u;
    }

    // wave-64 butterfly; per-half wave sums <= 64*items_per_thread << 65536 -> no carry
    #pragma unroll
    for (int m = 1; m < 64; m <<= 1) {
        #pragma unroll
        for (int p = 0; p < N_CLASSES; ++p)
            cnt[p] += __shfl_xor(cnt[p], m, 64);
    }

    // wave leaders -> block LDS (u32 per group: no 16-bit overflow at block level)
    if ((threadIdx.x & 63) == 0) {
        #pragma unroll
        for (int p = 0; p < N_CLASSES; ++p) {
            atomicAdd(&lh0[p], cnt[p] & 0xFFFFu);
            atomicAdd(&lh1[p], cnt[p] >> 16);
        }
    }
    __syncthreads();

    // plain stores — every block writes all 18 of its slots (d_ws is poison-filled, no memset needed)
    if (threadIdx.x < NBINS) {
        int c = threadIdx.x >> 1;
        unsigned int v = (threadIdx.x & 1) ? lh1[c] : lh0[c];
        partials[blockIdx.x * NBINS + threadIdx.x] = v;
    }
}

__global__ __launch_bounds__(1024) void spd_finalize_kernel(
    const unsigned int* __restrict__ partials,
    float* __restrict__ out, int nblocks, double n_total)
{
    __shared__ double counts[NBINS];
    const int tid = threadIdx.x;

    if (tid < NBINS * 32) {
        const int bin = tid >> 5;
        const int j = tid & 31;
        unsigned int s = 0u;
        for (int b = j; b < nblocks; b += 32)
            s += partials[b * NBINS + bin];
        #pragma unroll
        for (int m = 1; m < 32; m <<= 1)
            s += __shfl_xor(s, m, 32);
        if (j == 0) counts[bin] = (double)s;
    }
    __syncthreads();

    if (tid == 0) {
        double n1 = 0.0;
        #pragma unroll
        for (int c = 0; c < N_CLASSES; ++c)
            n1 += counts[c * N_GROUPS + 1];
        double n0 = n_total - n1;
        double acc = 0.0;
        #pragma unroll
        for (int c = 0; c < N_CLASSES; ++c) {
            double d = counts[c * N_GROUPS] / n0 - counts[c * N_GROUPS + 1] / n1;
            acc += d * d;
        }
        out[0] = (float)acc;
    }
}

extern "C" void kernel_launch(void* const* d_in, const int* in_sizes, int n_in,
                              void* d_out, int out_size, void* d_ws, size_t ws_size,
                              hipStream_t stream)
{
    const int* preds = (const int*)d_in[0];
    const int* attrs = (const int*)d_in[1];
    const int n = in_sizes[0];

    unsigned int* partials = (unsigned int*)d_ws;

    const int n4 = n / 4;
    const int block = 256;
    int grid = (n4 + block - 1) / block;
    if (grid > GRID_BLOCKS) grid = GRID_BLOCKS;
    // stay inside the provided workspace (each block needs NBINS u32s)
    int max_grid = (int)(ws_size / (NBINS * sizeof(unsigned int)));
    if (grid > max_grid) grid = max_grid;
    if (grid < 1) grid = 1;

    spd_hist_kernel<<<grid, block, 0, stream>>>(preds, attrs, partials, n4, n);
    spd_finalize_kernel<<<1, 1024, 0, stream>>>(partials, (float*)d_out, grid, (double)n);
}

// Round 4
// 151.792 us; speedup vs baseline: 1.0605x; 1.0293x over previous
//
#include <hip/hip_runtime.h>

// SPD loss: 18-bin (9 class x 2 group) histogram over 16.7M int32 pairs + tiny epilogue.
// R0: scattered LDS atomics -> 55 us.
// R1: register-packed histogram, same 55 us; warm==cold -> not LDS, not HBM.
// R2: removed global atomics -> 45 us, but warm==cold persists at 1.4 TB/s:
//     latency/MLP-bound — only 2 loads in flight per wave, 8 serial latency
//     exposures per thread (chunked grid-stride loop).
// R3: one superiteration per thread: ALL 16 independent 16-B loads issued
//     before any consumption (256 B/thread in flight). 1024 blocks x 512 thr
//     x 8 int4-pairs = n4 exactly. Finalize unrolled + 2x fewer partials.

#define N_CLASSES 9
#define N_GROUPS 2
#define NBINS (N_CLASSES * N_GROUPS)  // 18
#define ITEMS 8                       // int4-pairs per thread per superiteration (32 elems < 127 field cap)

__global__ __launch_bounds__(512) void spd_hist_kernel(
    const int* __restrict__ preds,
    const int* __restrict__ attrs,
    unsigned int* __restrict__ partials,  // [gridDim.x][NBINS]
    int n4, int n)
{
    __shared__ unsigned int lh0[N_CLASSES];
    __shared__ unsigned int lh1[N_CLASSES];
    if (threadIdx.x < N_CLASSES) { lh0[threadIdx.x] = 0u; lh1[threadIdx.x] = 0u; }
    __syncthreads();

    // per-thread 16-bit packed totals: lo16 = group0, hi16 = group1
    unsigned int cnt[N_CLASSES];
    #pragma unroll
    for (int p = 0; p < N_CLASSES; ++p) cnt[p] = 0u;

    const int4* __restrict__ p4 = (const int4*)preds;
    const int4* __restrict__ a4 = (const int4*)attrs;

    const int span = (int)blockDim.x * ITEMS;           // int4s covered by one block-superiteration
    for (int S = blockIdx.x * span; S < n4; S += gridDim.x * span) {
        const int s = S + (int)threadIdx.x;
        unsigned long long acc0 = 0ull, acc1 = 0ull;    // 9 fields x 7 bits, <=32 per field here

        if (S + span <= n4) {
            // fast path: issue all 16 loads before consuming anything (max MLP)
            int4 p[ITEMS], a[ITEMS];
            #pragma unroll
            for (int k = 0; k < ITEMS; ++k) p[k] = p4[s + k * (int)blockDim.x];
            #pragma unroll
            for (int k = 0; k < ITEMS; ++k) a[k] = a4[s + k * (int)blockDim.x];
            #pragma unroll
            for (int k = 0; k < ITEMS; ++k) {
                {
                    unsigned long long inc = 1ull << (7 * p[k].x);
                    acc0 += (a[k].x == 0) ? inc : 0ull;
                    acc1 += (a[k].x == 0) ? 0ull : inc;
                }
                {
                    unsigned long long inc = 1ull << (7 * p[k].y);
                    acc0 += (a[k].y == 0) ? inc : 0ull;
                    acc1 += (a[k].y == 0) ? 0ull : inc;
                }
                {
                    unsigned long long inc = 1ull << (7 * p[k].z);
                    acc0 += (a[k].z == 0) ? inc : 0ull;
                    acc1 += (a[k].z == 0) ? 0ull : inc;
                }
                {
                    unsigned long long inc = 1ull << (7 * p[k].w);
                    acc0 += (a[k].w == 0) ? inc : 0ull;
                    acc1 += (a[k].w == 0) ? 0ull : inc;
                }
            }
        } else {
            // masked tail superiteration
            for (int k = 0; k < ITEMS; ++k) {
                const int idx = s + k * (int)blockDim.x;
                if (idx < n4) {
                    int4 pp = p4[idx];
                    int4 aa = a4[idx];
                    {
                        unsigned long long inc = 1ull << (7 * pp.x);
                        acc0 += (aa.x == 0) ? inc : 0ull;
                        acc1 += (aa.x == 0) ? 0ull : inc;
                    }
                    {
                        unsigned long long inc = 1ull << (7 * pp.y);
                        acc0 += (aa.y == 0) ? inc : 0ull;
                        acc1 += (aa.y == 0) ? 0ull : inc;
                    }
                    {
                        unsigned long long inc = 1ull << (7 * pp.z);
                        acc0 += (aa.z == 0) ? inc : 0ull;
                        acc1 += (aa.z == 0) ? 0ull : inc;
                    }
                    {
                        unsigned long long inc = 1ull << (7 * pp.w);
                        acc0 += (aa.w == 0) ? inc : 0ull;
                        acc1 += (aa.w == 0) ? 0ull : inc;
                    }
                }
            }
        }

        // flush 7-bit window (<=32 per field) into 16-bit packed totals
        #pragma unroll
        for (int p = 0; p < N_CLASSES; ++p) {
            unsigned int c0 = (unsigned int)(acc0 >> (7 * p)) & 127u;
            unsigned int c1 = (unsigned int)(acc1 >> (7 * p)) & 127u;
            cnt[p] += c0 | (c1 << 16);
        }
    }

    // scalar remainder (n % 4), block 0 only: <=3 items
    if (blockIdx.x == 0) {
        for (int t = n4 * 4 + (int)threadIdx.x; t < n; t += (int)blockDim.x)
            cnt[preds[t]] += (attrs[t] == 0) ? 1u : 0x10000u;
    }

    // wave-64 butterfly; 16-bit halves hold <=64*32 = 2048 here — no carry
    #pragma unroll
    for (int m = 1; m < 64; m <<= 1) {
        #pragma unroll
        for (int p = 0; p < N_CLASSES; ++p)
            cnt[p] += __shfl_xor(cnt[p], m, 64);
    }

    // wave leaders -> block LDS (u32 per group)
    if ((threadIdx.x & 63) == 0) {
        #pragma unroll
        for (int p = 0; p < N_CLASSES; ++p) {
            atomicAdd(&lh0[p], cnt[p] & 0xFFFFu);
            atomicAdd(&lh1[p], cnt[p] >> 16);
        }
    }
    __syncthreads();

    // plain stores — no global atomics
    if (threadIdx.x < NBINS) {
        int c = threadIdx.x >> 1;
        unsigned int v = (threadIdx.x & 1) ? lh1[c] : lh0[c];
        partials[blockIdx.x * NBINS + threadIdx.x] = v;
    }
}

__global__ __launch_bounds__(1024) void spd_finalize_kernel(
    const unsigned int* __restrict__ partials,
    float* __restrict__ out, int nblocks, double n_total)
{
    __shared__ double counts[NBINS];
    const int tid = threadIdx.x;

    if (tid < NBINS * 32) {
        const int bin = tid >> 5;
        const int j = tid & 31;
        unsigned int s = 0u;
        #pragma unroll 8
        for (int b = j; b < nblocks; b += 32)
            s += partials[b * NBINS + bin];
        #pragma unroll
        for (int m = 1; m < 32; m <<= 1)
            s += __shfl_xor(s, m, 32);
        if (j == 0) counts[bin] = (double)s;
    }
    __syncthreads();

    if (tid == 0) {
        double n1 = 0.0;
        #pragma unroll
        for (int c = 0; c < N_CLASSES; ++c)
            n1 += counts[c * N_GROUPS + 1];
        double n0 = n_total - n1;
        double acc = 0.0;
        #pragma unroll
        for (int c = 0; c < N_CLASSES; ++c) {
            double d = counts[c * N_GROUPS] / n0 - counts[c * N_GROUPS + 1] / n1;
            acc += d * d;
        }
        out[0] = (float)acc;
    }
}

extern "C" void kernel_launch(void* const* d_in, const int* in_sizes, int n_in,
                              void* d_out, int out_size, void* d_ws, size_t ws_size,
                              hipStream_t stream)
{
    const int* preds = (const int*)d_in[0];
    const int* attrs = (const int*)d_in[1];
    const int n = in_sizes[0];

    unsigned int* partials = (unsigned int*)d_ws;

    const int n4 = n / 4;
    const int block = 512;
    const int per_block = block * ITEMS;              // int4s per block-superiteration
    int grid = (n4 + per_block - 1) / per_block;      // 1024 for N=16.7M
    if (grid > 2048) grid = 2048;
    int max_grid = (int)(ws_size / (NBINS * sizeof(unsigned int)));
    if (grid > max_grid) grid = max_grid;
    if (grid < 1) grid = 1;

    spd_hist_kernel<<<grid, block, 0, stream>>>(preds, attrs, partials, n4, n);
    spd_finalize_kernel<<<1, 1024, 0, stream>>>(partials, (float*)d_out, grid, (double)n);
}